// Round 6
// baseline (424.169 us; speedup 1.0000x reference)
//
#include <hip/hip_runtime.h>
#include <stdint.h>

// Problem constants (BERTNED): B=64, N=512, L=768, M=24, K=30, H=1024
#define B_   64
#define N_   512
#define L_   768
#define M_   24
#define K_   30
#define H_   1024
#define L2_  1536   // 2*L
#define BM_  (B_ * M_)      // 1536 rows of the span GEMM
#define BMK_ (B_ * M_ * K_) // 46080

typedef __attribute__((ext_vector_type(8))) short bf16x8;
typedef __attribute__((ext_vector_type(4))) float f32x4;

// round-to-nearest-even f32 -> bf16 (as raw ushort)
__device__ __forceinline__ ushort f2bf(float f) {
    union { float f; uint32_t u; } v; v.f = f;
    uint32_t u = v.u + 0x7FFFu + ((v.u >> 16) & 1u);
    return (ushort)(u >> 16);
}

// ---------------------------------------------------------------------------
// Standalone mask-width detect (used by fallback path).
// Any u32 word of the first B*M*K bytes not in {0,1,0x3F800000} => byte-packed.
// ---------------------------------------------------------------------------
__global__ void detect_mask_kernel(const uint32_t* __restrict__ mw,
                                   int* __restrict__ flag) {
    __shared__ int f;
    if (threadIdx.x == 0) f = 0;
    __syncthreads();
    int local = 0;
    const int nw = BMK_ / 4;
    for (int i = threadIdx.x; i < nw; i += blockDim.x) {
        uint32_t v = mw[i];
        if (v != 0u && v != 1u && v != 0x3F800000u) local = 1;
    }
    if (local) f = 1;              // benign same-value race
    __syncthreads();
    if (threadIdx.x == 0) *flag = f;
}

// ---------------------------------------------------------------------------
// Fused prep kernel (single launch, 3 independent block ranges):
//   blocks [0, BM_)            : gather span pair row bm -> bf16 pairB[bm][2L]
//   blocks [BM_, BM_+1536)     : W[2L][H] f32 -> Wt[H][2L] bf16 (32x32 tiles)
//   block  BM_+1536            : mask width detection
// ---------------------------------------------------------------------------
__global__ __launch_bounds__(256) void prep_kernel(
    const float* __restrict__ sent,
    const int*   __restrict__ sidx,
    const int*   __restrict__ eidx,
    const float* __restrict__ W,
    const uint32_t* __restrict__ maskw,
    ushort*      __restrict__ pairB,
    ushort*      __restrict__ Wt,
    int*         __restrict__ flag) {

    const int blk = blockIdx.x;
    const int t   = threadIdx.x;

    if (blk < BM_) {
        // ---- gather + convert one pair row (threads 0..191 active) ----
        if (t < 192) {
            const int bm = blk;
            const int l  = t * 8;                 // 0..1528, never straddles 768
            const int b  = bm / M_;
            int idx, ll;
            if (l < L_) { idx = sidx[bm]; ll = l; }
            else        { idx = eidx[bm]; ll = l - L_; }
            float4 v0 = make_float4(0.f, 0.f, 0.f, 0.f), v1 = v0;
            if (idx >= 0) {
                const float* src = sent + ((size_t)(b * N_ + idx)) * L_ + ll;
                v0 = *reinterpret_cast<const float4*>(src);
                v1 = *reinterpret_cast<const float4*>(src + 4);
            }
            ushort o[8] = { f2bf(v0.x), f2bf(v0.y), f2bf(v0.z), f2bf(v0.w),
                            f2bf(v1.x), f2bf(v1.y), f2bf(v1.z), f2bf(v1.w) };
            *reinterpret_cast<uint4*>(pairB + (size_t)bm * L2_ + l) =
                *reinterpret_cast<const uint4*>(o);
        }
    } else if (blk < BM_ + (L2_ / 32) * (H_ / 32)) {
        // ---- W transpose+convert, one 32x32 tile ----
        __shared__ ushort tile[32][33];
        const int idx = blk - BM_;
        const int l0  = (idx % (L2_ / 32)) * 32;
        const int h0  = (idx / (L2_ / 32)) * 32;
        {
            const int r  = t >> 3;
            const int c4 = (t & 7) * 4;
            const float4 v = *reinterpret_cast<const float4*>(
                W + (size_t)(l0 + r) * H_ + h0 + c4);
            tile[r][c4 + 0] = f2bf(v.x);
            tile[r][c4 + 1] = f2bf(v.y);
            tile[r][c4 + 2] = f2bf(v.z);
            tile[r][c4 + 3] = f2bf(v.w);
        }
        __syncthreads();
        {
            const int hr = t >> 3;
            const int l4 = (t & 7) * 4;
            ushort4 o;
            o.x = tile[l4 + 0][hr];
            o.y = tile[l4 + 1][hr];
            o.z = tile[l4 + 2][hr];
            o.w = tile[l4 + 3][hr];
            *reinterpret_cast<ushort4*>(Wt + (size_t)(h0 + hr) * L2_ + l0 + l4) = o;
        }
    } else {
        // ---- mask width detect ----
        __shared__ int f;
        if (t == 0) f = 0;
        __syncthreads();
        int local = 0;
        const int nw = BMK_ / 4;  // first 46080 bytes, in-bounds for all widths
        for (int i = t; i < nw; i += blockDim.x) {
            uint32_t v = maskw[i];
            if (v != 0u && v != 1u && v != 0x3F800000u) local = 1;
        }
        if (local) f = 1;          // benign same-value race
        __syncthreads();
        if (t == 0) *flag = f;
    }
}

// ---------------------------------------------------------------------------
// MFMA span GEMM: alias[BM][H] = pairB[BM][2L] x Wt[H][2L]^T + bias.
// 1 wave per block, 32x32 output tile (2x2 16x16x32 fragments), operands
// straight from global (K-contiguous, L2-resident panels).
// C/D mapping (verified m89/m91): col = lane&15, row = (lane>>4)*4 + reg.
// ---------------------------------------------------------------------------
__global__ __launch_bounds__(64) void mfma_span_gemm(
    const ushort* __restrict__ pairB,
    const ushort* __restrict__ WtB,
    const float*  __restrict__ bias,
    float*        __restrict__ alias_out) {

    const int lane = threadIdx.x;
    const int lr = lane & 15;      // fragment row/col index
    const int lg = lane >> 4;      // K-chunk group (8 elems each)
    const int c0 = blockIdx.x * 32;
    const int r0 = blockIdx.y * 32;

    f32x4 acc00 = {}, acc01 = {}, acc10 = {}, acc11 = {};

    const ushort* a0 = pairB + (size_t)(r0 + lr) * L2_ + lg * 8;
    const ushort* a1 = a0 + 16 * L2_;
    const ushort* b0 = WtB   + (size_t)(c0 + lr) * L2_ + lg * 8;
    const ushort* b1 = b0 + 16 * L2_;

#pragma unroll 4
    for (int k0 = 0; k0 < L2_; k0 += 32) {
        const bf16x8 av0 = *reinterpret_cast<const bf16x8*>(a0 + k0);
        const bf16x8 av1 = *reinterpret_cast<const bf16x8*>(a1 + k0);
        const bf16x8 bv0 = *reinterpret_cast<const bf16x8*>(b0 + k0);
        const bf16x8 bv1 = *reinterpret_cast<const bf16x8*>(b1 + k0);
        acc00 = __builtin_amdgcn_mfma_f32_16x16x32_bf16(av0, bv0, acc00, 0, 0, 0);
        acc01 = __builtin_amdgcn_mfma_f32_16x16x32_bf16(av0, bv1, acc01, 0, 0, 0);
        acc10 = __builtin_amdgcn_mfma_f32_16x16x32_bf16(av1, bv0, acc10, 0, 0, 0);
        acc11 = __builtin_amdgcn_mfma_f32_16x16x32_bf16(av1, bv1, acc11, 0, 0, 0);
    }

    const float bj0 = bias[c0 + lr];
    const float bj1 = bias[c0 + 16 + lr];
#pragma unroll
    for (int q = 0; q < 4; ++q) {
        const size_t rA = (size_t)(r0 + lg * 4 + q) * H_;
        const size_t rB = (size_t)(r0 + 16 + lg * 4 + q) * H_;
        alias_out[rA + c0 + lr]      = acc00[q] + bj0;
        alias_out[rA + c0 + 16 + lr] = acc01[q] + bj1;
        alias_out[rB + c0 + lr]      = acc10[q] + bj0;
        alias_out[rB + c0 + 16 + lr] = acc11[q] + bj1;
    }
}

// ---------------------------------------------------------------------------
// ent copy + scores, v2: persistent wave-per-row.  1536 blocks x 4 waves,
// grid-stride over the 46080 (b,m,k) rows.  Per row a wave streams 4 KB of
// ent (4 float4-chunks/lane), dots against the L2-resident alias row, one
// 6-shuffle reduce, no LDS / __syncthreads.  Wave-uniform mask branch.
// ---------------------------------------------------------------------------
#define ES_BLOCKS 1536
__global__ __launch_bounds__(256) void ent_scores_v2(
    const float* __restrict__ ent_in,
    const float* __restrict__ alias,
    const void*  __restrict__ mask,
    const int*   __restrict__ flag,
    float*       __restrict__ scores,
    float*       __restrict__ ent_out) {

    const int lane  = threadIdx.x & 63;
    const int wid   = blockIdx.x * 4 + (threadIdx.x >> 6);
    const int nwave = ES_BLOCKS * 4;

    const bool byte_packed = (*flag != 0);
    const uint8_t*  mb = (const uint8_t*)mask;
    const uint32_t* mw = (const uint32_t*)mask;

    for (int row = wid; row < BMK_; row += nwave) {
        const bool masked = byte_packed ? (mb[row] != 0) : (mw[row] != 0u);
        const size_t rowo = (size_t)row * H_;
        const int bm = row / K_;

        float p = 0.f;
        if (masked) {
            const float4 z = make_float4(0.f, 0.f, 0.f, 0.f);
#pragma unroll
            for (int c = 0; c < 4; ++c)
                *reinterpret_cast<float4*>(ent_out + rowo + c * 256 + lane * 4) = z;
        } else {
#pragma unroll
            for (int c = 0; c < 4; ++c) {
                const int off = c * 256 + lane * 4;
                const float4 e = *reinterpret_cast<const float4*>(ent_in + rowo + off);
                const float4 a = *reinterpret_cast<const float4*>(
                    alias + (size_t)bm * H_ + off);
                p += a.x * e.x + a.y * e.y + a.z * e.z + a.w * e.w;
                *reinterpret_cast<float4*>(ent_out + rowo + off) = e;
            }
        }
#pragma unroll
        for (int off = 32; off > 0; off >>= 1) p += __shfl_down(p, off);
        if (lane == 0) scores[row] = p;
    }
}

// ---------------------------------------------------------------------------
// Fallback f32 vector GEMM (used only if ws is too small for the bf16 path).
// ---------------------------------------------------------------------------
__global__ __launch_bounds__(256) void span_gemm_kernel(
    const float* __restrict__ sent,
    const int*   __restrict__ sidx,
    const int*   __restrict__ eidx,
    const float* __restrict__ W,
    const float* __restrict__ bias,
    float*       __restrict__ alias_out) {

    __shared__ float As[16][64];
    __shared__ float Bs[16][64];
    __shared__ int   offS[64];
    __shared__ int   offE[64];

    const int tid = threadIdx.x;
    const int bm0 = blockIdx.y * 64;
    const int h0  = blockIdx.x * 64;

    if (tid < 64) {
        const int bm = bm0 + tid;
        const int b  = bm / M_;
        const int si = sidx[bm];
        const int ei = eidx[bm];
        offS[tid] = (si < 0) ? -1 : (b * N_ + si) * L_;
        offE[tid] = (ei < 0) ? -1 : (b * N_ + ei) * L_;
    }
    __syncthreads();

    float acc[4][4] = {};
    const int ar  = tid >> 2;
    const int akq = (tid & 3) * 4;
    const int bkr = tid >> 4;
    const int bc  = (tid & 15) * 4;
    const int ty  = tid >> 4;
    const int tx  = tid & 15;

    for (int l0 = 0; l0 < L2_; l0 += 16) {
        {
            const int lb = l0 + akq;
            int off, ll;
            if (lb < L_) { off = offS[ar]; ll = lb; }
            else         { off = offE[ar]; ll = lb - L_; }
            float4 v;
            if (off < 0) v = make_float4(0.f, 0.f, 0.f, 0.f);
            else         v = *reinterpret_cast<const float4*>(sent + off + ll);
            As[akq + 0][ar] = v.x;  As[akq + 1][ar] = v.y;
            As[akq + 2][ar] = v.z;  As[akq + 3][ar] = v.w;
        }
        {
            const float4 v = *reinterpret_cast<const float4*>(
                W + (size_t)(l0 + bkr) * H_ + h0 + bc);
            *reinterpret_cast<float4*>(&Bs[bkr][bc]) = v;
        }
        __syncthreads();
#pragma unroll
        for (int k = 0; k < 16; ++k) {
            const float4 av = *reinterpret_cast<const float4*>(&As[k][ty * 4]);
            const float4 bv = *reinterpret_cast<const float4*>(&Bs[k][tx * 4]);
            acc[0][0] += av.x * bv.x; acc[0][1] += av.x * bv.y;
            acc[0][2] += av.x * bv.z; acc[0][3] += av.x * bv.w;
            acc[1][0] += av.y * bv.x; acc[1][1] += av.y * bv.y;
            acc[1][2] += av.y * bv.z; acc[1][3] += av.y * bv.w;
            acc[2][0] += av.z * bv.x; acc[2][1] += av.z * bv.y;
            acc[2][2] += av.z * bv.z; acc[2][3] += av.z * bv.w;
            acc[3][0] += av.w * bv.x; acc[3][1] += av.w * bv.y;
            acc[3][2] += av.w * bv.z; acc[3][3] += av.w * bv.w;
        }
        __syncthreads();
    }

    const float4 bb = *reinterpret_cast<const float4*>(bias + h0 + tx * 4);
#pragma unroll
    for (int i = 0; i < 4; ++i) {
        const int bm = bm0 + ty * 4 + i;
        const float4 o = make_float4(acc[i][0] + bb.x, acc[i][1] + bb.y,
                                     acc[i][2] + bb.z, acc[i][3] + bb.w);
        *reinterpret_cast<float4*>(alias_out + (size_t)bm * H_ + h0 + tx * 4) = o;
    }
}

// ---------------------------------------------------------------------------
extern "C" void kernel_launch(void* const* d_in, const int* in_sizes, int n_in,
                              void* d_out, int out_size, void* d_ws, size_t ws_size,
                              hipStream_t stream) {
    const float* sent = (const float*)d_in[0];   // (B,N,L) f32
    const float* ent  = (const float*)d_in[1];   // (B,M,K,H) f32
    const void*  mask = d_in[2];                 // (B,M,K) bool
    const int*   sidx = (const int*)d_in[3];     // (B,M) i32
    const int*   eidx = (const int*)d_in[4];     // (B,M) i32
    const float* W    = (const float*)d_in[5];   // (2L,H) f32
    const float* bias = (const float*)d_in[6];   // (H,) f32

    float* scores  = (float*)d_out;                          // B*M*K
    float* ent_out = (float*)d_out + (size_t)BMK_;           // B*M*K*H

    // ws layout: [0,256) flag | alias f32 (6.29 MB) | pairB bf16 (4.72 MB)
    //            | WtB bf16 (3.15 MB)
    const size_t ALIAS_B = (size_t)BM_ * H_ * 4;
    const size_t PAIR_B  = (size_t)BM_ * L2_ * 2;
    const size_t WT_B    = (size_t)H_ * L2_ * 2;

    int*    flag  = (int*)d_ws;
    float*  alias = (float*)((char*)d_ws + 256);
    ushort* pairB = (ushort*)((char*)d_ws + 256 + ALIAS_B);
    ushort* WtB   = (ushort*)((char*)d_ws + 256 + ALIAS_B + PAIR_B);

    if (ws_size >= 256 + ALIAS_B + PAIR_B + WT_B) {
        const int nprep = BM_ + (L2_ / 32) * (H_ / 32) + 1;  // 1536+1536+1
        prep_kernel<<<nprep, 256, 0, stream>>>(
            sent, sidx, eidx, W, (const uint32_t*)mask, pairB, WtB, flag);
        mfma_span_gemm<<<dim3(H_ / 32, BM_ / 32), 64, 0, stream>>>(
            pairB, WtB, bias, alias);
    } else {
        detect_mask_kernel<<<1, 256, 0, stream>>>((const uint32_t*)mask, flag);
        span_gemm_kernel<<<dim3(H_ / 64, BM_ / 64), 256, 0, stream>>>(
            sent, sidx, eidx, W, bias, alias);
    }

    ent_scores_v2<<<ES_BLOCKS, 256, 0, stream>>>(
        ent, alias, mask, flag, scores, ent_out);
}

// Round 8
// 397.891 us; speedup vs baseline: 1.0660x; 1.0660x over previous
//
#include <hip/hip_runtime.h>
#include <stdint.h>

// Problem constants (BERTNED): B=64, N=512, L=768, M=24, K=30, H=1024
#define B_   64
#define N_   512
#define L_   768
#define M_   24
#define K_   30
#define H_   1024
#define L2_  1536   // 2*L
#define BM_  (B_ * M_)      // 1536 rows of the span GEMM
#define BMK_ (B_ * M_ * K_) // 46080

typedef __attribute__((ext_vector_type(8))) short bf16x8;
typedef __attribute__((ext_vector_type(4))) float f32x4;

// round-to-nearest-even f32 -> bf16 (as raw ushort)
__device__ __forceinline__ ushort f2bf(float f) {
    union { float f; uint32_t u; } v; v.f = f;
    uint32_t u = v.u + 0x7FFFu + ((v.u >> 16) & 1u);
    return (ushort)(u >> 16);
}

// ---------------------------------------------------------------------------
// Standalone mask-width detect (used by fallback path).
// ---------------------------------------------------------------------------
__global__ void detect_mask_kernel(const uint32_t* __restrict__ mw,
                                   int* __restrict__ flag) {
    __shared__ int f;
    if (threadIdx.x == 0) f = 0;
    __syncthreads();
    int local = 0;
    const int nw = BMK_ / 4;
    for (int i = threadIdx.x; i < nw; i += blockDim.x) {
        uint32_t v = mw[i];
        if (v != 0u && v != 1u && v != 0x3F800000u) local = 1;
    }
    if (local) f = 1;              // benign same-value race
    __syncthreads();
    if (threadIdx.x == 0) *flag = f;
}

// ---------------------------------------------------------------------------
// Fused prep kernel (single launch, 3 independent block ranges):
//   blocks [0, BM_)            : gather span pair row bm -> bf16 pairB[bm][2L]
//   blocks [BM_, BM_+1536)     : W[2L][H] f32 -> Wt[H][2L] bf16 (32x32 tiles)
//   block  BM_+1536            : mask width detection
// ---------------------------------------------------------------------------
__global__ __launch_bounds__(256) void prep_kernel(
    const float* __restrict__ sent,
    const int*   __restrict__ sidx,
    const int*   __restrict__ eidx,
    const float* __restrict__ W,
    const uint32_t* __restrict__ maskw,
    ushort*      __restrict__ pairB,
    ushort*      __restrict__ Wt,
    int*         __restrict__ flag) {

    const int blk = blockIdx.x;
    const int t   = threadIdx.x;

    if (blk < BM_) {
        if (t < 192) {
            const int bm = blk;
            const int l  = t * 8;                 // 0..1528, never straddles 768
            const int b  = bm / M_;
            int idx, ll;
            if (l < L_) { idx = sidx[bm]; ll = l; }
            else        { idx = eidx[bm]; ll = l - L_; }
            float4 v0 = make_float4(0.f, 0.f, 0.f, 0.f), v1 = v0;
            if (idx >= 0) {
                const float* src = sent + ((size_t)(b * N_ + idx)) * L_ + ll;
                v0 = *reinterpret_cast<const float4*>(src);
                v1 = *reinterpret_cast<const float4*>(src + 4);
            }
            ushort o[8] = { f2bf(v0.x), f2bf(v0.y), f2bf(v0.z), f2bf(v0.w),
                            f2bf(v1.x), f2bf(v1.y), f2bf(v1.z), f2bf(v1.w) };
            *reinterpret_cast<uint4*>(pairB + (size_t)bm * L2_ + l) =
                *reinterpret_cast<const uint4*>(o);
        }
    } else if (blk < BM_ + (L2_ / 32) * (H_ / 32)) {
        __shared__ ushort tile[32][33];
        const int idx = blk - BM_;
        const int l0  = (idx % (L2_ / 32)) * 32;
        const int h0  = (idx / (L2_ / 32)) * 32;
        {
            const int r  = t >> 3;
            const int c4 = (t & 7) * 4;
            const float4 v = *reinterpret_cast<const float4*>(
                W + (size_t)(l0 + r) * H_ + h0 + c4);
            tile[r][c4 + 0] = f2bf(v.x);
            tile[r][c4 + 1] = f2bf(v.y);
            tile[r][c4 + 2] = f2bf(v.z);
            tile[r][c4 + 3] = f2bf(v.w);
        }
        __syncthreads();
        {
            const int hr = t >> 3;
            const int l4 = (t & 7) * 4;
            ushort4 o;
            o.x = tile[l4 + 0][hr];
            o.y = tile[l4 + 1][hr];
            o.z = tile[l4 + 2][hr];
            o.w = tile[l4 + 3][hr];
            *reinterpret_cast<ushort4*>(Wt + (size_t)(h0 + hr) * L2_ + l0 + l4) = o;
        }
    } else {
        __shared__ int f;
        if (t == 0) f = 0;
        __syncthreads();
        int local = 0;
        const int nw = BMK_ / 4;
        for (int i = t; i < nw; i += blockDim.x) {
            uint32_t v = maskw[i];
            if (v != 0u && v != 1u && v != 0x3F800000u) local = 1;
        }
        if (local) f = 1;
        __syncthreads();
        if (t == 0) *flag = f;
    }
}

// ---------------------------------------------------------------------------
// MFMA span GEMM v2: alias[BM][H] = pairB[BM][2L] x Wt[H][2L]^T + bias.
// 256-thread / 4-wave blocks, 64x64 tile (each wave one 32x32 quadrant),
// operands staged to LDS per K-step (4x less load traffic than per-wave),
// reg-staged with issue-early/write-late prefetch so L3/HBM latency hides
// under the MFMA phase.  LDS rows padded to 24 ushorts: ds_read_b128 2-way
// (free), ds_write 4-way.  Grid = (1024/64, 1536/64) = (16, 24) = 384 blocks.
// C/D mapping (HW-verified in rounds 4/6): col = lane&15, row=(lane>>4)*4+q.
// ---------------------------------------------------------------------------
__global__ __launch_bounds__(256) void mfma_span_gemm_v2(
    const ushort* __restrict__ pairB,
    const ushort* __restrict__ WtB,
    const float*  __restrict__ bias,
    float*        __restrict__ alias_out) {

    __shared__ ushort As[2][64][24];   // [k-half][row][k8(+pad)]
    __shared__ ushort Bs[2][64][24];   // [k-half][col][k8(+pad)]

    const int t    = threadIdx.x;
    const int lane = t & 63;
    const int w    = t >> 6;           // wave 0..3
    const int wr   = (w >> 1) * 32;    // wave row quadrant
    const int wc   = (w & 1) * 32;     // wave col quadrant
    const int lr   = lane & 15;        // fragment row/col
    const int lg   = lane >> 4;        // k-chunk group (8 elems)
    const int c0   = blockIdx.x * 64;
    const int r0   = blockIdx.y * 64;

    // staging decomposition: thread t covers chunk [sh][srow][sk8..sk8+8)
    const int sh   = t >> 7;           // k-half 0/1
    const int srow = (t >> 1) & 63;    // row/col within tile
    const int sk8  = (t & 1) * 8;      // k8 within half
    const ushort* aSrc = pairB + (size_t)(r0 + srow) * L2_ + sh * 16 + sk8;
    const ushort* bSrc = WtB   + (size_t)(c0 + srow) * L2_ + sh * 16 + sk8;

    f32x4 acc00 = {}, acc01 = {}, acc10 = {}, acc11 = {};

    uint4 va = *reinterpret_cast<const uint4*>(aSrc);       // k0 = 0
    uint4 vb = *reinterpret_cast<const uint4*>(bSrc);

    for (int k0 = 0; k0 < L2_; k0 += 32) {
        __syncthreads();   // previous step's reads complete; LDS reusable
        *reinterpret_cast<uint4*>(&As[sh][srow][sk8]) = va;
        *reinterpret_cast<uint4*>(&Bs[sh][srow][sk8]) = vb;
        // issue next step's loads now; latency hides under MFMA phase
        const int kn = (k0 + 32 < L2_) ? k0 + 32 : 0;
        va = *reinterpret_cast<const uint4*>(aSrc + kn);
        vb = *reinterpret_cast<const uint4*>(bSrc + kn);
        __syncthreads();   // staged data visible

        const bf16x8 a0 = *reinterpret_cast<const bf16x8*>(&As[lg >> 1][wr + lr]     [(lg & 1) * 8]);
        const bf16x8 a1 = *reinterpret_cast<const bf16x8*>(&As[lg >> 1][wr + 16 + lr][(lg & 1) * 8]);
        const bf16x8 b0 = *reinterpret_cast<const bf16x8*>(&Bs[lg >> 1][wc + lr]     [(lg & 1) * 8]);
        const bf16x8 b1 = *reinterpret_cast<const bf16x8*>(&Bs[lg >> 1][wc + 16 + lr][(lg & 1) * 8]);

        acc00 = __builtin_amdgcn_mfma_f32_16x16x32_bf16(a0, b0, acc00, 0, 0, 0);
        acc01 = __builtin_amdgcn_mfma_f32_16x16x32_bf16(a0, b1, acc01, 0, 0, 0);
        acc10 = __builtin_amdgcn_mfma_f32_16x16x32_bf16(a1, b0, acc10, 0, 0, 0);
        acc11 = __builtin_amdgcn_mfma_f32_16x16x32_bf16(a1, b1, acc11, 0, 0, 0);
    }

    const float bj0 = bias[c0 + wc + lr];
    const float bj1 = bias[c0 + wc + 16 + lr];
#pragma unroll
    for (int q = 0; q < 4; ++q) {
        const size_t rA = (size_t)(r0 + wr + lg * 4 + q) * H_;
        const size_t rB = (size_t)(r0 + wr + 16 + lg * 4 + q) * H_;
        alias_out[rA + c0 + wc + lr]      = acc00[q] + bj0;
        alias_out[rA + c0 + wc + 16 + lr] = acc01[q] + bj1;
        alias_out[rB + c0 + wc + lr]      = acc10[q] + bj0;
        alias_out[rB + c0 + wc + 16 + lr] = acc11[q] + bj1;
    }
}

// ---------------------------------------------------------------------------
// ent copy + scores, v3: persistent wave-per-row, max occupancy (2048 blocks
// x 4 waves = 32 waves/CU), nontemporal on the big no-reuse ent stream.
// ---------------------------------------------------------------------------
#define ES_BLOCKS 2048
__global__ __launch_bounds__(256) void ent_scores_v3(
    const float* __restrict__ ent_in,
    const float* __restrict__ alias,
    const void*  __restrict__ mask,
    const int*   __restrict__ flag,
    float*       __restrict__ scores,
    float*       __restrict__ ent_out) {

    const int lane  = threadIdx.x & 63;
    const int wid   = blockIdx.x * 4 + (threadIdx.x >> 6);
    const int nwave = ES_BLOCKS * 4;

    const bool byte_packed = (*flag != 0);
    const uint8_t*  mb = (const uint8_t*)mask;
    const uint32_t* mw = (const uint32_t*)mask;

    for (int row = wid; row < BMK_; row += nwave) {
        const bool masked = byte_packed ? (mb[row] != 0) : (mw[row] != 0u);
        const size_t rowo = (size_t)row * H_;
        const int bm = row / K_;

        float p = 0.f;
        if (masked) {
            const f32x4 z = {};
#pragma unroll
            for (int c = 0; c < 4; ++c)
                __builtin_nontemporal_store(
                    z, reinterpret_cast<f32x4*>(ent_out + rowo + c * 256 + lane * 4));
        } else {
#pragma unroll
            for (int c = 0; c < 4; ++c) {
                const int off = c * 256 + lane * 4;
                const f32x4 e = __builtin_nontemporal_load(
                    reinterpret_cast<const f32x4*>(ent_in + rowo + off));
                const f32x4 a = *reinterpret_cast<const f32x4*>(
                    alias + (size_t)bm * H_ + off);
                p += a[0] * e[0] + a[1] * e[1] + a[2] * e[2] + a[3] * e[3];
                __builtin_nontemporal_store(
                    e, reinterpret_cast<f32x4*>(ent_out + rowo + off));
            }
        }
#pragma unroll
        for (int off = 32; off > 0; off >>= 1) p += __shfl_down(p, off);
        if (lane == 0) scores[row] = p;
    }
}

// ---------------------------------------------------------------------------
// Fallback f32 vector GEMM (used only if ws is too small for the bf16 path).
// ---------------------------------------------------------------------------
__global__ __launch_bounds__(256) void span_gemm_kernel(
    const float* __restrict__ sent,
    const int*   __restrict__ sidx,
    const int*   __restrict__ eidx,
    const float* __restrict__ W,
    const float* __restrict__ bias,
    float*       __restrict__ alias_out) {

    __shared__ float As[16][64];
    __shared__ float Bs[16][64];
    __shared__ int   offS[64];
    __shared__ int   offE[64];

    const int tid = threadIdx.x;
    const int bm0 = blockIdx.y * 64;
    const int h0  = blockIdx.x * 64;

    if (tid < 64) {
        const int bm = bm0 + tid;
        const int b  = bm / M_;
        const int si = sidx[bm];
        const int ei = eidx[bm];
        offS[tid] = (si < 0) ? -1 : (b * N_ + si) * L_;
        offE[tid] = (ei < 0) ? -1 : (b * N_ + ei) * L_;
    }
    __syncthreads();

    float acc[4][4] = {};
    const int ar  = tid >> 2;
    const int akq = (tid & 3) * 4;
    const int bkr = tid >> 4;
    const int bc  = (tid & 15) * 4;
    const int ty  = tid >> 4;
    const int tx  = tid & 15;

    for (int l0 = 0; l0 < L2_; l0 += 16) {
        {
            const int lb = l0 + akq;
            int off, ll;
            if (lb < L_) { off = offS[ar]; ll = lb; }
            else         { off = offE[ar]; ll = lb - L_; }
            float4 v;
            if (off < 0) v = make_float4(0.f, 0.f, 0.f, 0.f);
            else         v = *reinterpret_cast<const float4*>(sent + off + ll);
            As[akq + 0][ar] = v.x;  As[akq + 1][ar] = v.y;
            As[akq + 2][ar] = v.z;  As[akq + 3][ar] = v.w;
        }
        {
            const float4 v = *reinterpret_cast<const float4*>(
                W + (size_t)(l0 + bkr) * H_ + h0 + bc);
            *reinterpret_cast<float4*>(&Bs[bkr][bc]) = v;
        }
        __syncthreads();
#pragma unroll
        for (int k = 0; k < 16; ++k) {
            const float4 av = *reinterpret_cast<const float4*>(&As[k][ty * 4]);
            const float4 bv = *reinterpret_cast<const float4*>(&Bs[k][tx * 4]);
            acc[0][0] += av.x * bv.x; acc[0][1] += av.x * bv.y;
            acc[0][2] += av.x * bv.z; acc[0][3] += av.x * bv.w;
            acc[1][0] += av.y * bv.x; acc[1][1] += av.y * bv.y;
            acc[1][2] += av.y * bv.z; acc[1][3] += av.y * bv.w;
            acc[2][0] += av.z * bv.x; acc[2][1] += av.z * bv.y;
            acc[2][2] += av.z * bv.z; acc[2][3] += av.z * bv.w;
            acc[3][0] += av.w * bv.x; acc[3][1] += av.w * bv.y;
            acc[3][2] += av.w * bv.z; acc[3][3] += av.w * bv.w;
        }
        __syncthreads();
    }

    const float4 bb = *reinterpret_cast<const float4*>(bias + h0 + tx * 4);
#pragma unroll
    for (int i = 0; i < 4; ++i) {
        const int bm = bm0 + ty * 4 + i;
        const float4 o = make_float4(acc[i][0] + bb.x, acc[i][1] + bb.y,
                                     acc[i][2] + bb.z, acc[i][3] + bb.w);
        *reinterpret_cast<float4*>(alias_out + (size_t)bm * H_ + h0 + tx * 4) = o;
    }
}

// ---------------------------------------------------------------------------
extern "C" void kernel_launch(void* const* d_in, const int* in_sizes, int n_in,
                              void* d_out, int out_size, void* d_ws, size_t ws_size,
                              hipStream_t stream) {
    const float* sent = (const float*)d_in[0];   // (B,N,L) f32
    const float* ent  = (const float*)d_in[1];   // (B,M,K,H) f32
    const void*  mask = d_in[2];                 // (B,M,K) bool
    const int*   sidx = (const int*)d_in[3];     // (B,M) i32
    const int*   eidx = (const int*)d_in[4];     // (B,M) i32
    const float* W    = (const float*)d_in[5];   // (2L,H) f32
    const float* bias = (const float*)d_in[6];   // (H,) f32

    float* scores  = (float*)d_out;                          // B*M*K
    float* ent_out = (float*)d_out + (size_t)BMK_;           // B*M*K*H

    // ws layout: [0,256) flag | alias f32 (6.29 MB) | pairB bf16 (4.72 MB)
    //            | WtB bf16 (3.15 MB)
    const size_t ALIAS_B = (size_t)BM_ * H_ * 4;
    const size_t PAIR_B  = (size_t)BM_ * L2_ * 2;
    const size_t WT_B    = (size_t)H_ * L2_ * 2;

    int*    flag  = (int*)d_ws;
    float*  alias = (float*)((char*)d_ws + 256);
    ushort* pairB = (ushort*)((char*)d_ws + 256 + ALIAS_B);
    ushort* WtB   = (ushort*)((char*)d_ws + 256 + ALIAS_B + PAIR_B);

    if (ws_size >= 256 + ALIAS_B + PAIR_B + WT_B) {
        const int nprep = BM_ + (L2_ / 32) * (H_ / 32) + 1;  // 1536+1536+1
        prep_kernel<<<nprep, 256, 0, stream>>>(
            sent, sidx, eidx, W, (const uint32_t*)mask, pairB, WtB, flag);
        mfma_span_gemm_v2<<<dim3(H_ / 64, BM_ / 64), 256, 0, stream>>>(
            pairB, WtB, bias, alias);
    } else {
        detect_mask_kernel<<<1, 256, 0, stream>>>((const uint32_t*)mask, flag);
        span_gemm_kernel<<<dim3(H_ / 64, BM_ / 64), 256, 0, stream>>>(
            sent, sidx, eidx, W, bias, alias);
    }

    ent_scores_v3<<<ES_BLOCKS, 256, 0, stream>>>(
        ent, alias, mask, flag, scores, ent_out);
}